// Round 6
// baseline (630.438 us; speedup 1.0000x reference)
//
#include <hip/hip_runtime.h>
#include <hip/hip_bf16.h>

// ---------------- shapes ----------------
#define Bdim 2
#define Tdim 1024
#define DMODEL 2048
#define DSTATE 64
#define HEADDIM 64
#define DCONV 4
#define DINNER 4096
#define NHEADS 64
#define CONVDIM 4224           // DINNER + 2*DSTATE
#define DINPROJ 8384           // 2*DINNER + 2*DSTATE + NHEADS
#define NPAD 8448              // DINPROJ padded to multiple of 128
#define MROWS (Bdim*Tdim)      // 2048
#define QC 64                  // scan chunk length
#define NCHUNK (Tdim/QC)       // 16

typedef __attribute__((ext_vector_type(8))) short bf16x8;
typedef __attribute__((ext_vector_type(4))) float f32x4;
typedef __attribute__((ext_vector_type(4))) unsigned short u16x4;

#define GLB(p) ((const __attribute__((address_space(1))) void*)(p))
#define LDS(p) ((__attribute__((address_space(3))) void*)(p))

__device__ __forceinline__ unsigned short f2bf(float f) {
    unsigned int x = __builtin_bit_cast(unsigned int, f);
    x += 0x7fffu + ((x >> 16) & 1u);   // RNE
    return (unsigned short)(x >> 16);
}
__device__ __forceinline__ float bf2f(unsigned int u16) {
    unsigned int x = u16 << 16;
    return __builtin_bit_cast(float, x);
}
__device__ __forceinline__ float siluf(float v) {
    return v / (1.f + expf(-v));
}

// ------- fused fp32->bf16 weight convert (both weights, float4) -------------
// seg A: in_proj (8384 x 2048) -> win (8448 x 2048, zero-padded rows)
// seg B: out_proj (2048 x 4096) -> wout
#define CVT_A4 (NPAD * DMODEL / 4)        // 4,325,376
#define CVT_B4 (DMODEL * DINNER / 4)      // 2,097,152
__global__ __launch_bounds__(256) void cvtpad_k(const float* __restrict__ in_proj,
                                                const float* __restrict__ out_proj,
                                                unsigned short* __restrict__ win,
                                                unsigned short* __restrict__ wout) {
    int idx = blockIdx.x * 256 + threadIdx.x;
    if (idx < CVT_A4) {
        int i4 = idx * 4;
        int row = i4 >> 11;               // /DMODEL
        u16x4 o;
        if (row < DINPROJ) {
            float4 v = *(const float4*)(in_proj + i4);
            o = (u16x4){f2bf(v.x), f2bf(v.y), f2bf(v.z), f2bf(v.w)};
        } else {
            o = (u16x4){0, 0, 0, 0};
        }
        *(u16x4*)(win + i4) = o;
    } else {
        int i4 = (idx - CVT_A4) * 4;
        float4 v = *(const float4*)(out_proj + i4);
        *(u16x4*)(wout + i4) = (u16x4){f2bf(v.x), f2bf(v.y), f2bf(v.z), f2bf(v.w)};
    }
}

// ---------------- LayerNorm: x fp32 -> u bf16 (float4) ----------------
__global__ __launch_bounds__(256) void layernorm_k(const float* __restrict__ x,
                                                   const float* __restrict__ w,
                                                   const float* __restrict__ b,
                                                   unsigned short* __restrict__ u) {
    int row = blockIdx.x;
    const float* xr = x + (size_t)row * DMODEL;
    float4 v[2];
    float s = 0.f, s2 = 0.f;
#pragma unroll
    for (int i = 0; i < 2; ++i) {
        int c = (threadIdx.x + 256 * i) * 4;
        v[i] = *(const float4*)(xr + c);
        s += v[i].x + v[i].y + v[i].z + v[i].w;
        s2 += v[i].x * v[i].x + v[i].y * v[i].y + v[i].z * v[i].z + v[i].w * v[i].w;
    }
#pragma unroll
    for (int off = 32; off; off >>= 1) { s += __shfl_down(s, off); s2 += __shfl_down(s2, off); }
    __shared__ float rs[4], rs2[4];
    if ((threadIdx.x & 63) == 0) { rs[threadIdx.x >> 6] = s; rs2[threadIdx.x >> 6] = s2; }
    __syncthreads();
    s = rs[0] + rs[1] + rs[2] + rs[3];
    s2 = rs2[0] + rs2[1] + rs2[2] + rs2[3];
    float mu = s * (1.f / DMODEL);
    float var = s2 * (1.f / DMODEL) - mu * mu;
    float inv = rsqrtf(var + 1e-5f);
#pragma unroll
    for (int i = 0; i < 2; ++i) {
        int c = (threadIdx.x + 256 * i) * 4;
        float4 wv = *(const float4*)(w + c);
        float4 bv = *(const float4*)(b + c);
        u16x4 o = {f2bf((v[i].x - mu) * inv * wv.x + bv.x),
                   f2bf((v[i].y - mu) * inv * wv.y + bv.y),
                   f2bf((v[i].z - mu) * inv * wv.z + bv.z),
                   f2bf((v[i].w - mu) * inv * wv.w + bv.w)};
        *(u16x4*)(u + (size_t)row * DMODEL + c) = o;
    }
}

// ---------------- bf16 GEMM, B given as (N x K) row-major ("B^T" form) -------
// global_load_lds width=16; LDS layout [quad_k][row][8] -> 2-way-conflict b128
// reads. 1D grid with 8-wide n-panel swizzle for L2 reuse.
template <int EPI>
__global__ __launch_bounds__(256) void gemm_bt(const unsigned short* __restrict__ A,
                                               const unsigned short* __restrict__ Bw,
                                               float* __restrict__ Cout,
                                               const float* __restrict__ resid,
                                               int N, int K, int lda, int nb, int mb) {
    // panel swizzle
    const int bid = blockIdx.x;
    const int per_panel = mb * 8;
    const int fullp = (nb / 8) * per_panel;
    int mt, nt;
    if (bid < fullp) {
        int p = bid / per_panel, r = bid % per_panel;
        nt = p * 8 + r / mb; mt = r % mb;
    } else {
        int r = bid - fullp;
        nt = (nb / 8) * 8 + r / mb; mt = r % mb;
    }
    const int m0 = mt * 128, n0 = nt * 128;

    __shared__ unsigned short As[4096];   // [quad 4][row 128][8 shorts]
    __shared__ unsigned short Bs[4096];
    const int tid = threadIdx.x;
    const int lane = tid & 63, w = tid >> 6;
    const int wm = (w >> 1) * 64, wn = (w & 1) * 64;
    const int row16 = lane & 15, quad = lane >> 4;

    // staging source: thread tid loads row (tid&127), k-col (tid>>7)*8 (+16 for issue 1)
    const int srow = tid & 127, sq = tid >> 7;
    const unsigned short* gA = A + (size_t)(m0 + srow) * lda + sq * 8;
    const unsigned short* gB = Bw + (size_t)(n0 + srow) * K + sq * 8;

    f32x4 acc[4][4];
#pragma unroll
    for (int i = 0; i < 4; ++i)
#pragma unroll
        for (int j = 0; j < 4; ++j) acc[i][j] = (f32x4){0.f, 0.f, 0.f, 0.f};

    for (int k0 = 0; k0 < K; k0 += 32) {
        __builtin_amdgcn_global_load_lds(GLB(gA + k0),      LDS(As + tid * 8),        16, 0, 0);
        __builtin_amdgcn_global_load_lds(GLB(gA + k0 + 16), LDS(As + 2048 + tid * 8), 16, 0, 0);
        __builtin_amdgcn_global_load_lds(GLB(gB + k0),      LDS(Bs + tid * 8),        16, 0, 0);
        __builtin_amdgcn_global_load_lds(GLB(gB + k0 + 16), LDS(Bs + 2048 + tid * 8), 16, 0, 0);
        __syncthreads();

        bf16x8 af[4], bfr[4];
#pragma unroll
        for (int i = 0; i < 4; ++i) af[i] = *(const bf16x8*)&As[quad * 1024 + (wm + i * 16 + row16) * 8];
#pragma unroll
        for (int j = 0; j < 4; ++j) bfr[j] = *(const bf16x8*)&Bs[quad * 1024 + (wn + j * 16 + row16) * 8];
#pragma unroll
        for (int i = 0; i < 4; ++i)
#pragma unroll
            for (int j = 0; j < 4; ++j)
                acc[i][j] = __builtin_amdgcn_mfma_f32_16x16x32_bf16(af[i], bfr[j], acc[i][j], 0, 0, 0);
        __syncthreads();
    }

#pragma unroll
    for (int i = 0; i < 4; ++i)
#pragma unroll
        for (int j = 0; j < 4; ++j)
#pragma unroll
            for (int r = 0; r < 4; ++r) {
                int m = m0 + wm + i * 16 + quad * 4 + r;
                int n = n0 + wn + j * 16 + row16;
                float v = acc[i][j][r];
                if (EPI == 0)
                    Cout[(size_t)m * N + n] = v;
                else
                    Cout[(size_t)m * N + n] = resid[(size_t)m * N + n] + v;
            }
}

// -------- fused causal conv4+SiLU (vec4) + dt/softplus (vec4) ----------------
// blocks [0, 8448): conv over (bt, c4); blocks [8448, 8576): dt over (bt, h4)
#define CONV_T (MROWS * CONVDIM / 4)      // 2,162,688
__global__ __launch_bounds__(256) void convdt_k(const float* __restrict__ zx,
                                                const float* __restrict__ cw,
                                                const float* __restrict__ cb,
                                                const float* __restrict__ dt_bias,
                                                const float* __restrict__ A_log,
                                                float* __restrict__ xin,
                                                float* __restrict__ bcf,
                                                float* __restrict__ dtf,
                                                float* __restrict__ dtAf) {
    int idx = blockIdx.x * 256 + threadIdx.x;
    if (idx < CONV_T) {
        int cg = idx % (CONVDIM / 4);
        int bt = idx / (CONVDIM / 4);
        int c = cg * 4;
        int t = bt & (Tdim - 1);
        const float* base = zx + (size_t)bt * NPAD + DINNER + c;
        float4 acc = *(const float4*)(cb + c);
#pragma unroll
        for (int kk = 0; kk < DCONV; ++kk) {
            int tt = t - 3 + kk;
            if (tt >= 0) {
                float4 v = *(const float4*)(base + (long)(kk - 3) * NPAD);
                acc.x += v.x * cw[(c + 0) * 4 + kk];
                acc.y += v.y * cw[(c + 1) * 4 + kk];
                acc.z += v.z * cw[(c + 2) * 4 + kk];
                acc.w += v.w * cw[(c + 3) * 4 + kk];
            }
        }
        float4 s = {siluf(acc.x), siluf(acc.y), siluf(acc.z), siluf(acc.w)};
        if (c < DINNER) *(float4*)(xin + (size_t)bt * DINNER + c) = s;
        else            *(float4*)(bcf + (size_t)bt * 128 + (c - DINNER)) = s;
    } else {
        int d4 = (idx - CONV_T) * 4;
        int bt = d4 >> 6;
        int h = d4 & 63;
        float4 raw = *(const float4*)(zx + (size_t)bt * NPAD + (DINNER + CONVDIM) + h);
        float4 bias = *(const float4*)(dt_bias + h);
        float4 al = *(const float4*)(A_log + h);
        float r[4] = {raw.x + bias.x, raw.y + bias.y, raw.z + bias.z, raw.w + bias.w};
        float A[4] = {-expf(al.x), -expf(al.y), -expf(al.z), -expf(al.w)};
        float4 dtv, dta;
        float* dtp = (float*)&dtv; float* dap = (float*)&dta;
#pragma unroll
        for (int j = 0; j < 4; ++j) {
            float dv = (r[j] > 20.f) ? r[j] : log1pf(expf(r[j]));
            dtp[j] = dv;
            dap[j] = dv * A[j];
        }
        *(float4*)(dtf + bt * 64 + h) = dtv;
        *(float4*)(dtAf + bt * 64 + h) = dta;
    }
}

// ============ chunked SSM scan (SSD decomposition), Q=64 =====================
// Phase A: per (b,h,chunk): S[p][n] = sum_i exp(laQ - la_i) * dtx_i[p] * B_i[n]
__global__ __launch_bounds__(256) void chunk_state_k(const float* __restrict__ xin,
                                                     const float* __restrict__ bcf,
                                                     const float* __restrict__ dtf,
                                                     const float* __restrict__ dtAf,
                                                     float* __restrict__ Sst,
                                                     float* __restrict__ laq) {
    const int blk = blockIdx.x;
    const int c = blk & 15, h = (blk >> 4) & 63, b = blk >> 10;
    const int bt0 = b * Tdim + c * QC;
    const int tid = threadIdx.x;

    __shared__ float Bs[QC][68];
    __shared__ float Dx[QC][68];
    __shared__ float wsh[QC];

    if (tid < QC) {
        float v = dtAf[(bt0 + tid) * NHEADS + h];
#pragma unroll
        for (int d = 1; d < 64; d <<= 1) {
            float o = __shfl_up(v, d, 64);
            v += (tid >= d) ? o : 0.f;
        }
        float la63 = __shfl(v, 63, 64);
        wsh[tid] = expf(la63 - v);       // weight for step i
        if (tid == 63) laq[blk] = la63;  // chunk total log-decay
    }
    __syncthreads();

    const int row = tid >> 2, q = tid & 3;
    {
        float m = wsh[row] * dtf[(bt0 + row) * NHEADS + h];
        const float* xr = xin + (size_t)(bt0 + row) * DINNER + h * 64 + q * 16;
        const float* br = bcf + (size_t)(bt0 + row) * 128 + q * 16;
#pragma unroll
        for (int j = 0; j < 4; ++j) {
            float4 xv = *(const float4*)(xr + j * 4);
            float4 bv = *(const float4*)(br + j * 4);
            *(float4*)&Dx[row][q * 16 + j * 4] = (float4){m * xv.x, m * xv.y, m * xv.z, m * xv.w};
            *(float4*)&Bs[row][q * 16 + j * 4] = bv;
        }
    }
    __syncthreads();

    const int p0 = (tid >> 4) * 4, n0 = (tid & 15) * 4;
    float acc[4][4] = {};
    for (int i = 0; i < QC; ++i) {
        float4 dv = *(const float4*)&Dx[i][p0];
        float4 bv = *(const float4*)&Bs[i][n0];
        float dva[4] = {dv.x, dv.y, dv.z, dv.w};
        float bva[4] = {bv.x, bv.y, bv.z, bv.w};
#pragma unroll
        for (int a = 0; a < 4; ++a)
#pragma unroll
            for (int e = 0; e < 4; ++e) acc[a][e] += dva[a] * bva[e];
    }
    float* Sp = Sst + (size_t)blk * NPAD;
#pragma unroll
    for (int a = 0; a < 4; ++a)
        *(float4*)&Sp[(p0 + a) * 64 + n0] = (float4){acc[a][0], acc[a][1], acc[a][2], acc[a][3]};
}

// Phase B: per (b,h): running prefix of states across chunks (in place)
__global__ __launch_bounds__(256) void combine_k(float* __restrict__ Sst,
                                                 const float* __restrict__ laq) {
    const int bh = blockIdx.x;
    const int tid = threadIdx.x;
    float4 r0 = {}, r1 = {}, r2 = {}, r3 = {};
    for (int c = 0; c < NCHUNK - 1; ++c) {
        float* p = Sst + (size_t)(bh * 16 + c) * NPAD + tid * 16;
        float P = expf(laq[bh * 16 + c]);
        float4 s0 = ((const float4*)p)[0], s1 = ((const float4*)p)[1];
        float4 s2 = ((const float4*)p)[2], s3 = ((const float4*)p)[3];
        r0 = (float4){P * r0.x + s0.x, P * r0.y + s0.y, P * r0.z + s0.z, P * r0.w + s0.w};
        r1 = (float4){P * r1.x + s1.x, P * r1.y + s1.y, P * r1.z + s1.z, P * r1.w + s1.w};
        r2 = (float4){P * r2.x + s2.x, P * r2.y + s2.y, P * r2.z + s2.z, P * r2.w + s2.w};
        r3 = (float4){P * r3.x + s3.x, P * r3.y + s3.y, P * r3.z + s3.z, P * r3.w + s3.w};
        ((float4*)p)[0] = r0; ((float4*)p)[1] = r1;
        ((float4*)p)[2] = r2; ((float4*)p)[3] = r3;
    }
}

// Phase C: per (b,h,chunk): Y = (L.(C@B^T))@dtx + exp(la).(hinit@C^T) + D*x
// LDS kept under 64 KB (61,696 B): dtx tile staged as bf16.
__global__ __launch_bounds__(256) void chunk_out_k(float* __restrict__ xin,
                                                   const float* __restrict__ bcf,
                                                   const float* __restrict__ dtf,
                                                   const float* __restrict__ dtAf,
                                                   const float* __restrict__ Sst,
                                                   const float* __restrict__ Dp) {
    const int blk = blockIdx.x;
    const int c = blk & 15, h = (blk >> 4) & 63, b = blk >> 10;
    const int bt0 = b * Tdim + c * QC;
    const int tid = threadIdx.x;

    __shared__ float Cs[QC][68];             // [t][n]
    __shared__ float BsT[QC][68];            // [n][s]; later reused as hT [n][p]
    __shared__ unsigned short Dxh[QC][72];   // [s][p]  dt*x in bf16
    __shared__ float G[QC][68];              // [t][s]
    __shared__ float lash[QC];

    if (tid < QC) {
        float v = dtAf[(bt0 + tid) * NHEADS + h];
#pragma unroll
        for (int d = 1; d < 64; d <<= 1) {
            float o = __shfl_up(v, d, 64);
            v += (tid >= d) ? o : 0.f;
        }
        lash[tid] = v;
    }

    const int row = tid >> 2, q = tid & 3;
    {
        float m = dtf[(bt0 + row) * NHEADS + h];
        const float* xr = xin + (size_t)(bt0 + row) * DINNER + h * 64 + q * 16;
        const float* br = bcf + (size_t)(bt0 + row) * 128 + q * 16;        // B
        const float* cr = bcf + (size_t)(bt0 + row) * 128 + 64 + q * 16;   // C
#pragma unroll
        for (int j = 0; j < 4; ++j) {
            float4 xv = *(const float4*)(xr + j * 4);
            float4 bv = *(const float4*)(br + j * 4);
            float4 cv = *(const float4*)(cr + j * 4);
            unsigned int w0 = (unsigned int)f2bf(m * xv.x) | ((unsigned int)f2bf(m * xv.y) << 16);
            unsigned int w1 = (unsigned int)f2bf(m * xv.z) | ((unsigned int)f2bf(m * xv.w) << 16);
            *(uint2*)&Dxh[row][q * 16 + j * 4] = (uint2){w0, w1};
            *(float4*)&Cs[row][q * 16 + j * 4] = cv;
            int n = q * 16 + j * 4;
            BsT[n + 0][row] = bv.x; BsT[n + 1][row] = bv.y;
            BsT[n + 2][row] = bv.z; BsT[n + 3][row] = bv.w;
        }
    }
    __syncthreads();

    // ---- G = masked/decayed C @ B^T ----
    const int t0 = (tid >> 4) * 4, s0 = (tid & 15) * 4;
    {
        float acc[4][4] = {};
        for (int n = 0; n < 64; ++n) {
            float4 bv = *(const float4*)&BsT[n][s0];
            float bva[4] = {bv.x, bv.y, bv.z, bv.w};
            float cva[4] = {Cs[t0 + 0][n], Cs[t0 + 1][n], Cs[t0 + 2][n], Cs[t0 + 3][n]};
#pragma unroll
            for (int a = 0; a < 4; ++a)
#pragma unroll
                for (int e = 0; e < 4; ++e) acc[a][e] += cva[a] * bva[e];
        }
        float lat[4] = {lash[t0 + 0], lash[t0 + 1], lash[t0 + 2], lash[t0 + 3]};
#pragma unroll
        for (int a = 0; a < 4; ++a)
#pragma unroll
            for (int e = 0; e < 4; ++e) {
                int t = t0 + a, s = s0 + e;
                G[t][s] = (s <= t) ? acc[a][e] * expf(lat[a] - lash[s]) : 0.f;
            }
    }
    __syncthreads();

    // ---- load hinit (transposed) into BsT ----
    if (c > 0) {
        const float* Hp = Sst + (size_t)(blk - 1) * NPAD;   // slot c-1
#pragma unroll
        for (int j = 0; j < 4; ++j) {
            float4 hv = *(const float4*)&Hp[row * 64 + q * 16 + j * 4];
            int n = q * 16 + j * 4;
            BsT[n + 0][row] = hv.x; BsT[n + 1][row] = hv.y;
            BsT[n + 2][row] = hv.z; BsT[n + 3][row] = hv.w;   // hT[n][p]
        }
    }
    __syncthreads();

    // ---- Y ----
    const int p0 = (tid & 15) * 4;
    float accS[4][4] = {};
    for (int s = 0; s < 64; ++s) {
        uint2 dw = *(const uint2*)&Dxh[s][p0];
        float dva[4] = {bf2f(dw.x & 0xffffu), bf2f(dw.x >> 16),
                        bf2f(dw.y & 0xffffu), bf2f(dw.y >> 16)};
        float gva[4] = {G[t0 + 0][s], G[t0 + 1][s], G[t0 + 2][s], G[t0 + 3][s]};
#pragma unroll
        for (int a = 0; a < 4; ++a)
#pragma unroll
            for (int e = 0; e < 4; ++e) accS[a][e] += gva[a] * dva[e];
    }
    float accH[4][4] = {};
    if (c > 0) {
        for (int n = 0; n < 64; ++n) {
            float4 hv = *(const float4*)&BsT[n][p0];
            float hva[4] = {hv.x, hv.y, hv.z, hv.w};
            float cva[4] = {Cs[t0 + 0][n], Cs[t0 + 1][n], Cs[t0 + 2][n], Cs[t0 + 3][n]};
#pragma unroll
            for (int a = 0; a < 4; ++a)
#pragma unroll
                for (int e = 0; e < 4; ++e) accH[a][e] += cva[a] * hva[e];
        }
    }
    float Dh = Dp[h];
    float eA[4] = {expf(lash[t0 + 0]), expf(lash[t0 + 1]), expf(lash[t0 + 2]), expf(lash[t0 + 3])};
#pragma unroll
    for (int a = 0; a < 4; ++a) {
        float* xr = xin + (size_t)(bt0 + t0 + a) * DINNER + h * 64 + p0;
        float4 xv = *(const float4*)xr;
        float4 yv;
        yv.x = accS[a][0] + eA[a] * accH[a][0] + Dh * xv.x;
        yv.y = accS[a][1] + eA[a] * accH[a][1] + Dh * xv.y;
        yv.z = accS[a][2] + eA[a] * accH[a][2] + Dh * xv.z;
        yv.w = accS[a][3] + eA[a] * accH[a][3] + Dh * xv.w;
        *(float4*)xr = yv;
    }
}

// ---------------- y * silu(z), RMSNorm, -> bf16 (strided dest, vec4) ---------
__global__ __launch_bounds__(256) void gate_k(const float* __restrict__ ybf,
                                              const float* __restrict__ zx,
                                              const float* __restrict__ nw,
                                              unsigned short* __restrict__ yg,
                                              int ldyg) {
    int row = blockIdx.x;
    float4 tv[4];
    float s2 = 0.f;
#pragma unroll
    for (int i = 0; i < 4; ++i) {
        int c = (threadIdx.x + 256 * i) * 4;
        float4 y = *(const float4*)(ybf + (size_t)row * DINNER + c);
        float4 z = *(const float4*)(zx + (size_t)row * NPAD + c);
        float4 t = {y.x * siluf(z.x), y.y * siluf(z.y), y.z * siluf(z.z), y.w * siluf(z.w)};
        tv[i] = t;
        s2 += t.x * t.x + t.y * t.y + t.z * t.z + t.w * t.w;
    }
#pragma unroll
    for (int off = 32; off; off >>= 1) s2 += __shfl_down(s2, off);
    __shared__ float rs[4];
    if ((threadIdx.x & 63) == 0) rs[threadIdx.x >> 6] = s2;
    __syncthreads();
    s2 = rs[0] + rs[1] + rs[2] + rs[3];
    float scale = rsqrtf(s2 * (1.f / DINNER) + 1e-5f);
#pragma unroll
    for (int i = 0; i < 4; ++i) {
        int c = (threadIdx.x + 256 * i) * 4;
        float4 w = *(const float4*)(nw + c);
        u16x4 o = {f2bf(tv[i].x * scale * w.x), f2bf(tv[i].y * scale * w.y),
                   f2bf(tv[i].z * scale * w.z), f2bf(tv[i].w * scale * w.w)};
        *(u16x4*)(yg + (size_t)row * ldyg + c) = o;
    }
}

// ---------------- launch ----------------
extern "C" void kernel_launch(void* const* d_in, const int* in_sizes, int n_in,
                              void* d_out, int out_size, void* d_ws, size_t ws_size,
                              hipStream_t stream) {
    const float* x        = (const float*)d_in[0];
    const float* ln_w     = (const float*)d_in[1];
    const float* ln_b     = (const float*)d_in[2];
    const float* in_proj  = (const float*)d_in[3];
    const float* conv_w   = (const float*)d_in[4];
    const float* conv_b   = (const float*)d_in[5];
    const float* dt_bias  = (const float*)d_in[6];
    const float* A_log    = (const float*)d_in[7];
    const float* Dp       = (const float*)d_in[8];
    const float* norm_w   = (const float*)d_in[9];
    const float* out_proj = (const float*)d_in[10];
    float* out = (float*)d_out;
    char* ws = (char*)d_ws;

    // ---- workspace layout ----
    float*          zx   = (float*)(ws + 0);                   // 2048 x 8448 fp32
    unsigned short* wout = (unsigned short*)(ws + 69206016);
    unsigned short* win  = (unsigned short*)(ws + 85983232);
    unsigned short* ubf  = (unsigned short*)(ws + 120586240);
    float*          xin  = (float*)(ws + 85983232);            // reuses win after GEMM1
    float*          bcf  = (float*)(ws + 120586240);           // reuses ubf
    float*          dtf  = (float*)(ws + 121634816);
    float*          dtAf = (float*)(ws + 122159104);
    float*          laq  = (float*)(ws + 122683392);           // 2048 floats
    // S states live in dead xBC columns of zx: slot blk -> zx row blk, cols [4096,8192)
    float*          Sst  = zx + 4096;                          // row stride NPAD
    // yg bf16 packed into dead columns of zx (written AFTER scan completes)
    unsigned short* yg   = (unsigned short*)zx + 8192;
    const int       ldyg = 16896;

    cvtpad_k<<<(CVT_A4 + CVT_B4) / 256, 256, 0, stream>>>(in_proj, out_proj, win, wout);
    layernorm_k<<<MROWS, 256, 0, stream>>>(x, ln_w, ln_b, ubf);
    // GEMM1: zxbcdt = u @ in_proj^T  (M=2048, N=8448, K=2048), fp32 out
    gemm_bt<0><<<(NPAD / 128) * (MROWS / 128), 256, 0, stream>>>(ubf, win, zx, nullptr,
                                                                 NPAD, DMODEL, DMODEL,
                                                                 NPAD / 128, MROWS / 128);
    convdt_k<<<(CONV_T + MROWS * NHEADS / 4) / 256, 256, 0, stream>>>(zx, conv_w, conv_b,
                                                                      dt_bias, A_log,
                                                                      xin, bcf, dtf, dtAf);
    // chunked scan
    chunk_state_k<<<Bdim * NHEADS * NCHUNK, 256, 0, stream>>>(xin, bcf, dtf, dtAf, Sst, laq);
    combine_k<<<Bdim * NHEADS, 256, 0, stream>>>(Sst, laq);
    chunk_out_k<<<Bdim * NHEADS * NCHUNK, 256, 0, stream>>>(xin, bcf, dtf, dtAf, Sst, Dp);
    // epilogue
    gate_k<<<MROWS, 256, 0, stream>>>(xin, zx, norm_w, yg, ldyg);
    // GEMM2: out = x + yg @ out_proj^T  (M=2048, N=2048, K=4096), fp32 out
    gemm_bt<1><<<(DMODEL / 128) * (MROWS / 128), 256, 0, stream>>>(yg, wout, out, x,
                                                                   DMODEL, DINNER, ldyg,
                                                                   DMODEL / 128, MROWS / 128);
}

// Round 7
// 544.627 us; speedup vs baseline: 1.1576x; 1.1576x over previous
//
#include <hip/hip_runtime.h>
#include <hip/hip_bf16.h>

// ---------------- shapes ----------------
#define Bdim 2
#define Tdim 1024
#define DMODEL 2048
#define DSTATE 64
#define HEADDIM 64
#define DCONV 4
#define DINNER 4096
#define NHEADS 64
#define CONVDIM 4224           // DINNER + 2*DSTATE
#define DINPROJ 8384           // 2*DINNER + 2*DSTATE + NHEADS
#define NPAD 8448              // DINPROJ padded to multiple of 128
#define MROWS (Bdim*Tdim)      // 2048
#define QC 64                  // scan chunk length
#define NCHUNK (Tdim/QC)       // 16

typedef __attribute__((ext_vector_type(8))) short bf16x8;
typedef __attribute__((ext_vector_type(4))) float f32x4;
typedef __attribute__((ext_vector_type(4))) unsigned short u16x4;

#define GLB(p) ((const __attribute__((address_space(1))) void*)(p))
#define LDS(p) ((__attribute__((address_space(3))) void*)(p))

__device__ __forceinline__ unsigned short f2bf(float f) {
    unsigned int x = __builtin_bit_cast(unsigned int, f);
    x += 0x7fffu + ((x >> 16) & 1u);   // RNE
    return (unsigned short)(x >> 16);
}
__device__ __forceinline__ float bf2f(unsigned int u16) {
    unsigned int x = u16 << 16;
    return __builtin_bit_cast(float, x);
}
__device__ __forceinline__ float siluf(float v) {
    return v / (1.f + expf(-v));
}

// ------- fused fp32->bf16 weight convert (both weights, float4) -------------
#define CVT_A4 (NPAD * DMODEL / 4)        // 4,325,376
#define CVT_B4 (DMODEL * DINNER / 4)      // 2,097,152
__global__ __launch_bounds__(256) void cvtpad_k(const float* __restrict__ in_proj,
                                                const float* __restrict__ out_proj,
                                                unsigned short* __restrict__ win,
                                                unsigned short* __restrict__ wout) {
    int idx = blockIdx.x * 256 + threadIdx.x;
    if (idx < CVT_A4) {
        int i4 = idx * 4;
        int row = i4 >> 11;               // /DMODEL
        u16x4 o;
        if (row < DINPROJ) {
            float4 v = *(const float4*)(in_proj + i4);
            o = (u16x4){f2bf(v.x), f2bf(v.y), f2bf(v.z), f2bf(v.w)};
        } else {
            o = (u16x4){0, 0, 0, 0};
        }
        *(u16x4*)(win + i4) = o;
    } else {
        int i4 = (idx - CVT_A4) * 4;
        float4 v = *(const float4*)(out_proj + i4);
        *(u16x4*)(wout + i4) = (u16x4){f2bf(v.x), f2bf(v.y), f2bf(v.z), f2bf(v.w)};
    }
}

// ---------------- LayerNorm: x fp32 -> u bf16 (float4) ----------------
__global__ __launch_bounds__(256) void layernorm_k(const float* __restrict__ x,
                                                   const float* __restrict__ w,
                                                   const float* __restrict__ b,
                                                   unsigned short* __restrict__ u) {
    int row = blockIdx.x;
    const float* xr = x + (size_t)row * DMODEL;
    float4 v[2];
    float s = 0.f, s2 = 0.f;
#pragma unroll
    for (int i = 0; i < 2; ++i) {
        int c = (threadIdx.x + 256 * i) * 4;
        v[i] = *(const float4*)(xr + c);
        s += v[i].x + v[i].y + v[i].z + v[i].w;
        s2 += v[i].x * v[i].x + v[i].y * v[i].y + v[i].z * v[i].z + v[i].w * v[i].w;
    }
#pragma unroll
    for (int off = 32; off; off >>= 1) { s += __shfl_down(s, off); s2 += __shfl_down(s2, off); }
    __shared__ float rs[4], rs2[4];
    if ((threadIdx.x & 63) == 0) { rs[threadIdx.x >> 6] = s; rs2[threadIdx.x >> 6] = s2; }
    __syncthreads();
    s = rs[0] + rs[1] + rs[2] + rs[3];
    s2 = rs2[0] + rs2[1] + rs2[2] + rs2[3];
    float mu = s * (1.f / DMODEL);
    float var = s2 * (1.f / DMODEL) - mu * mu;
    float inv = rsqrtf(var + 1e-5f);
#pragma unroll
    for (int i = 0; i < 2; ++i) {
        int c = (threadIdx.x + 256 * i) * 4;
        float4 wv = *(const float4*)(w + c);
        float4 bv = *(const float4*)(b + c);
        u16x4 o = {f2bf((v[i].x - mu) * inv * wv.x + bv.x),
                   f2bf((v[i].y - mu) * inv * wv.y + bv.y),
                   f2bf((v[i].z - mu) * inv * wv.z + bv.z),
                   f2bf((v[i].w - mu) * inv * wv.w + bv.w)};
        *(u16x4*)(u + (size_t)row * DMODEL + c) = o;
    }
}

// ---------------- bf16 GEMM, B given as (N x K) row-major ("B^T" form) -------
// global_load_lds width=16 with XOR-swizzled LDS layout:
//   element (row, kb) at 16B-group (row*4 + (kb ^ s(row))), s(r)=(r&3)^((r>>2)&3)
// -> staging stays 64B-coalesced AND fragment ds_read_b128 is 2-way (free).
template <int EPI>
__global__ __launch_bounds__(256) void gemm_bt(const unsigned short* __restrict__ A,
                                               const unsigned short* __restrict__ Bw,
                                               float* __restrict__ Cout,
                                               const float* __restrict__ resid,
                                               int N, int K, int lda, int nb, int mb) {
    // panel swizzle (8 n-tiles per panel) for L2 reuse
    const int bid = blockIdx.x;
    const int per_panel = mb * 8;
    const int fullp = (nb / 8) * per_panel;
    int mt, nt;
    if (bid < fullp) {
        int p = bid / per_panel, r = bid % per_panel;
        nt = p * 8 + r / mb; mt = r % mb;
    } else {
        int r = bid - fullp;
        nt = (nb / 8) * 8 + r / mb; mt = r % mb;
    }
    const int m0 = mt * 128, n0 = nt * 128;

    __shared__ unsigned short As[4096];   // 8 KB: [row 128][kb 4][8 shorts], kb xor-swizzled
    __shared__ unsigned short Bs[4096];
    const int tid = threadIdx.x;
    const int lane = tid & 63, w = tid >> 6;
    const int wm = (w >> 1) * 64, wn = (w & 1) * 64;
    const int row16 = lane & 15, quad = lane >> 4;

    // staging: thread tid -> row = tid>>2 (and +64), kb = (tid&3) ^ s(row)
    const int srow = tid >> 2;
    const int skb = (tid & 3) ^ ((srow & 3) ^ ((srow >> 2) & 3));   // s(row+64)==s(row)
    const unsigned short* gA0 = A + (size_t)(m0 + srow) * lda + skb * 8;
    const unsigned short* gA1 = A + (size_t)(m0 + 64 + srow) * lda + skb * 8;
    const unsigned short* gB0 = Bw + (size_t)(n0 + srow) * K + skb * 8;
    const unsigned short* gB1 = Bw + (size_t)(n0 + 64 + srow) * K + skb * 8;

    // fragment read column for this lane
    const int sl = (row16 & 3) ^ ((row16 >> 2) & 3);
    const int kcol = ((quad ^ sl) * 8);

    f32x4 acc[4][4];
#pragma unroll
    for (int i = 0; i < 4; ++i)
#pragma unroll
        for (int j = 0; j < 4; ++j) acc[i][j] = (f32x4){0.f, 0.f, 0.f, 0.f};

    for (int k0 = 0; k0 < K; k0 += 32) {
        __builtin_amdgcn_global_load_lds(GLB(gA0 + k0), LDS(As + tid * 8),        16, 0, 0);
        __builtin_amdgcn_global_load_lds(GLB(gA1 + k0), LDS(As + 2048 + tid * 8), 16, 0, 0);
        __builtin_amdgcn_global_load_lds(GLB(gB0 + k0), LDS(Bs + tid * 8),        16, 0, 0);
        __builtin_amdgcn_global_load_lds(GLB(gB1 + k0), LDS(Bs + 2048 + tid * 8), 16, 0, 0);
        __syncthreads();

        bf16x8 af[4], bfr[4];
#pragma unroll
        for (int i = 0; i < 4; ++i) af[i] = *(const bf16x8*)&As[(wm + i * 16 + row16) * 32 + kcol];
#pragma unroll
        for (int j = 0; j < 4; ++j) bfr[j] = *(const bf16x8*)&Bs[(wn + j * 16 + row16) * 32 + kcol];
#pragma unroll
        for (int i = 0; i < 4; ++i)
#pragma unroll
            for (int j = 0; j < 4; ++j)
                acc[i][j] = __builtin_amdgcn_mfma_f32_16x16x32_bf16(af[i], bfr[j], acc[i][j], 0, 0, 0);
        __syncthreads();
    }

#pragma unroll
    for (int i = 0; i < 4; ++i)
#pragma unroll
        for (int j = 0; j < 4; ++j)
#pragma unroll
            for (int r = 0; r < 4; ++r) {
                int m = m0 + wm + i * 16 + quad * 4 + r;
                int n = n0 + wn + j * 16 + row16;
                float v = acc[i][j][r];
                if (EPI == 0)
                    Cout[(size_t)m * N + n] = v;
                else
                    Cout[(size_t)m * N + n] = resid[(size_t)m * N + n] + v;
            }
}

// -------- fused causal conv4+SiLU (vec4) + dt/softplus (vec4) ----------------
#define CONV_T (MROWS * CONVDIM / 4)      // 2,162,688
__global__ __launch_bounds__(256) void convdt_k(const float* __restrict__ zx,
                                                const float* __restrict__ cw,
                                                const float* __restrict__ cb,
                                                const float* __restrict__ dt_bias,
                                                const float* __restrict__ A_log,
                                                float* __restrict__ xin,
                                                float* __restrict__ bcf,
                                                float* __restrict__ dtf,
                                                float* __restrict__ dtAf) {
    int idx = blockIdx.x * 256 + threadIdx.x;
    if (idx < CONV_T) {
        int cg = idx % (CONVDIM / 4);
        int bt = idx / (CONVDIM / 4);
        int c = cg * 4;
        int t = bt & (Tdim - 1);
        const float* base = zx + (size_t)bt * NPAD + DINNER + c;
        float4 acc = *(const float4*)(cb + c);
#pragma unroll
        for (int kk = 0; kk < DCONV; ++kk) {
            int tt = t - 3 + kk;
            if (tt >= 0) {
                float4 v = *(const float4*)(base + (long)(kk - 3) * NPAD);
                acc.x += v.x * cw[(c + 0) * 4 + kk];
                acc.y += v.y * cw[(c + 1) * 4 + kk];
                acc.z += v.z * cw[(c + 2) * 4 + kk];
                acc.w += v.w * cw[(c + 3) * 4 + kk];
            }
        }
        float4 s = {siluf(acc.x), siluf(acc.y), siluf(acc.z), siluf(acc.w)};
        if (c < DINNER) *(float4*)(xin + (size_t)bt * DINNER + c) = s;
        else            *(float4*)(bcf + (size_t)bt * 128 + (c - DINNER)) = s;
    } else {
        int d4 = (idx - CONV_T) * 4;
        int bt = d4 >> 6;
        int h = d4 & 63;
        float4 raw = *(const float4*)(zx + (size_t)bt * NPAD + (DINNER + CONVDIM) + h);
        float4 bias = *(const float4*)(dt_bias + h);
        float4 al = *(const float4*)(A_log + h);
        float r[4] = {raw.x + bias.x, raw.y + bias.y, raw.z + bias.z, raw.w + bias.w};
        float A[4] = {-expf(al.x), -expf(al.y), -expf(al.z), -expf(al.w)};
        float4 dtv, dta;
        float* dtp = (float*)&dtv; float* dap = (float*)&dta;
#pragma unroll
        for (int j = 0; j < 4; ++j) {
            float dv = (r[j] > 20.f) ? r[j] : log1pf(expf(r[j]));
            dtp[j] = dv;
            dap[j] = dv * A[j];
        }
        *(float4*)(dtf + bt * 64 + h) = dtv;
        *(float4*)(dtAf + bt * 64 + h) = dta;
    }
}

// ============ chunked SSM scan (SSD decomposition), Q=64 =====================
__global__ __launch_bounds__(256) void chunk_state_k(const float* __restrict__ xin,
                                                     const float* __restrict__ bcf,
                                                     const float* __restrict__ dtf,
                                                     const float* __restrict__ dtAf,
                                                     float* __restrict__ Sst,
                                                     float* __restrict__ laq) {
    const int blk = blockIdx.x;
    const int c = blk & 15, h = (blk >> 4) & 63, b = blk >> 10;
    const int bt0 = b * Tdim + c * QC;
    const int tid = threadIdx.x;

    __shared__ float Bs[QC][68];
    __shared__ float Dx[QC][68];
    __shared__ float wsh[QC];

    if (tid < QC) {
        float v = dtAf[(bt0 + tid) * NHEADS + h];
#pragma unroll
        for (int d = 1; d < 64; d <<= 1) {
            float o = __shfl_up(v, d, 64);
            v += (tid >= d) ? o : 0.f;
        }
        float la63 = __shfl(v, 63, 64);
        wsh[tid] = expf(la63 - v);
        if (tid == 63) laq[blk] = la63;
    }
    __syncthreads();

    const int row = tid >> 2, q = tid & 3;
    {
        float m = wsh[row] * dtf[(bt0 + row) * NHEADS + h];
        const float* xr = xin + (size_t)(bt0 + row) * DINNER + h * 64 + q * 16;
        const float* br = bcf + (size_t)(bt0 + row) * 128 + q * 16;
#pragma unroll
        for (int j = 0; j < 4; ++j) {
            float4 xv = *(const float4*)(xr + j * 4);
            float4 bv = *(const float4*)(br + j * 4);
            *(float4*)&Dx[row][q * 16 + j * 4] = (float4){m * xv.x, m * xv.y, m * xv.z, m * xv.w};
            *(float4*)&Bs[row][q * 16 + j * 4] = bv;
        }
    }
    __syncthreads();

    const int p0 = (tid >> 4) * 4, n0 = (tid & 15) * 4;
    float acc[4][4] = {};
    for (int i = 0; i < QC; ++i) {
        float4 dv = *(const float4*)&Dx[i][p0];
        float4 bv = *(const float4*)&Bs[i][n0];
        float dva[4] = {dv.x, dv.y, dv.z, dv.w};
        float bva[4] = {bv.x, bv.y, bv.z, bv.w};
#pragma unroll
        for (int a = 0; a < 4; ++a)
#pragma unroll
            for (int e = 0; e < 4; ++e) acc[a][e] += dva[a] * bva[e];
    }
    float* Sp = Sst + (size_t)blk * NPAD;
#pragma unroll
    for (int a = 0; a < 4; ++a)
        *(float4*)&Sp[(p0 + a) * 64 + n0] = (float4){acc[a][0], acc[a][1], acc[a][2], acc[a][3]};
}

__global__ __launch_bounds__(256) void combine_k(float* __restrict__ Sst,
                                                 const float* __restrict__ laq) {
    const int bh = blockIdx.x;
    const int tid = threadIdx.x;
    float4 r0 = {}, r1 = {}, r2 = {}, r3 = {};
    for (int c = 0; c < NCHUNK - 1; ++c) {
        float* p = Sst + (size_t)(bh * 16 + c) * NPAD + tid * 16;
        float P = expf(laq[bh * 16 + c]);
        float4 s0 = ((const float4*)p)[0], s1 = ((const float4*)p)[1];
        float4 s2 = ((const float4*)p)[2], s3 = ((const float4*)p)[3];
        r0 = (float4){P * r0.x + s0.x, P * r0.y + s0.y, P * r0.z + s0.z, P * r0.w + s0.w};
        r1 = (float4){P * r1.x + s1.x, P * r1.y + s1.y, P * r1.z + s1.z, P * r1.w + s1.w};
        r2 = (float4){P * r2.x + s2.x, P * r2.y + s2.y, P * r2.z + s2.z, P * r2.w + s2.w};
        r3 = (float4){P * r3.x + s3.x, P * r3.y + s3.y, P * r3.z + s3.z, P * r3.w + s3.w};
        ((float4*)p)[0] = r0; ((float4*)p)[1] = r1;
        ((float4*)p)[2] = r2; ((float4*)p)[3] = r3;
    }
}

__global__ __launch_bounds__(256) void chunk_out_k(float* __restrict__ xin,
                                                   const float* __restrict__ bcf,
                                                   const float* __restrict__ dtf,
                                                   const float* __restrict__ dtAf,
                                                   const float* __restrict__ Sst,
                                                   const float* __restrict__ Dp) {
    const int blk = blockIdx.x;
    const int c = blk & 15, h = (blk >> 4) & 63, b = blk >> 10;
    const int bt0 = b * Tdim + c * QC;
    const int tid = threadIdx.x;

    __shared__ float Cs[QC][68];
    __shared__ float BsT[QC][68];
    __shared__ unsigned short Dxh[QC][72];
    __shared__ float G[QC][68];
    __shared__ float lash[QC];

    if (tid < QC) {
        float v = dtAf[(bt0 + tid) * NHEADS + h];
#pragma unroll
        for (int d = 1; d < 64; d <<= 1) {
            float o = __shfl_up(v, d, 64);
            v += (tid >= d) ? o : 0.f;
        }
        lash[tid] = v;
    }

    const int row = tid >> 2, q = tid & 3;
    {
        float m = dtf[(bt0 + row) * NHEADS + h];
        const float* xr = xin + (size_t)(bt0 + row) * DINNER + h * 64 + q * 16;
        const float* br = bcf + (size_t)(bt0 + row) * 128 + q * 16;
        const float* cr = bcf + (size_t)(bt0 + row) * 128 + 64 + q * 16;
#pragma unroll
        for (int j = 0; j < 4; ++j) {
            float4 xv = *(const float4*)(xr + j * 4);
            float4 bv = *(const float4*)(br + j * 4);
            float4 cv = *(const float4*)(cr + j * 4);
            unsigned int w0 = (unsigned int)f2bf(m * xv.x) | ((unsigned int)f2bf(m * xv.y) << 16);
            unsigned int w1 = (unsigned int)f2bf(m * xv.z) | ((unsigned int)f2bf(m * xv.w) << 16);
            *(uint2*)&Dxh[row][q * 16 + j * 4] = (uint2){w0, w1};
            *(float4*)&Cs[row][q * 16 + j * 4] = cv;
            int n = q * 16 + j * 4;
            BsT[n + 0][row] = bv.x; BsT[n + 1][row] = bv.y;
            BsT[n + 2][row] = bv.z; BsT[n + 3][row] = bv.w;
        }
    }
    __syncthreads();

    const int t0 = (tid >> 4) * 4, s0 = (tid & 15) * 4;
    {
        float acc[4][4] = {};
        for (int n = 0; n < 64; ++n) {
            float4 bv = *(const float4*)&BsT[n][s0];
            float bva[4] = {bv.x, bv.y, bv.z, bv.w};
            float cva[4] = {Cs[t0 + 0][n], Cs[t0 + 1][n], Cs[t0 + 2][n], Cs[t0 + 3][n]};
#pragma unroll
            for (int a = 0; a < 4; ++a)
#pragma unroll
                for (int e = 0; e < 4; ++e) acc[a][e] += cva[a] * bva[e];
        }
        float lat[4] = {lash[t0 + 0], lash[t0 + 1], lash[t0 + 2], lash[t0 + 3]};
#pragma unroll
        for (int a = 0; a < 4; ++a)
#pragma unroll
            for (int e = 0; e < 4; ++e) {
                int t = t0 + a, s = s0 + e;
                G[t][s] = (s <= t) ? acc[a][e] * expf(lat[a] - lash[s]) : 0.f;
            }
    }
    __syncthreads();

    if (c > 0) {
        const float* Hp = Sst + (size_t)(blk - 1) * NPAD;
#pragma unroll
        for (int j = 0; j < 4; ++j) {
            float4 hv = *(const float4*)&Hp[row * 64 + q * 16 + j * 4];
            int n = q * 16 + j * 4;
            BsT[n + 0][row] = hv.x; BsT[n + 1][row] = hv.y;
            BsT[n + 2][row] = hv.z; BsT[n + 3][row] = hv.w;
        }
    }
    __syncthreads();

    const int p0 = (tid & 15) * 4;
    float accS[4][4] = {};
    for (int s = 0; s < 64; ++s) {
        uint2 dw = *(const uint2*)&Dxh[s][p0];
        float dva[4] = {bf2f(dw.x & 0xffffu), bf2f(dw.x >> 16),
                        bf2f(dw.y & 0xffffu), bf2f(dw.y >> 16)};
        float gva[4] = {G[t0 + 0][s], G[t0 + 1][s], G[t0 + 2][s], G[t0 + 3][s]};
#pragma unroll
        for (int a = 0; a < 4; ++a)
#pragma unroll
            for (int e = 0; e < 4; ++e) accS[a][e] += gva[a] * dva[e];
    }
    float accH[4][4] = {};
    if (c > 0) {
        for (int n = 0; n < 64; ++n) {
            float4 hv = *(const float4*)&BsT[n][p0];
            float hva[4] = {hv.x, hv.y, hv.z, hv.w};
            float cva[4] = {Cs[t0 + 0][n], Cs[t0 + 1][n], Cs[t0 + 2][n], Cs[t0 + 3][n]};
#pragma unroll
            for (int a = 0; a < 4; ++a)
#pragma unroll
                for (int e = 0; e < 4; ++e) accH[a][e] += cva[a] * hva[e];
        }
    }
    float Dh = Dp[h];
    float eA[4] = {expf(lash[t0 + 0]), expf(lash[t0 + 1]), expf(lash[t0 + 2]), expf(lash[t0 + 3])};
#pragma unroll
    for (int a = 0; a < 4; ++a) {
        float* xr = xin + (size_t)(bt0 + t0 + a) * DINNER + h * 64 + p0;
        float4 xv = *(const float4*)xr;
        float4 yv;
        yv.x = accS[a][0] + eA[a] * accH[a][0] + Dh * xv.x;
        yv.y = accS[a][1] + eA[a] * accH[a][1] + Dh * xv.y;
        yv.z = accS[a][2] + eA[a] * accH[a][2] + Dh * xv.z;
        yv.w = accS[a][3] + eA[a] * accH[a][3] + Dh * xv.w;
        *(float4*)xr = yv;
    }
}

// ---------------- y * silu(z), RMSNorm, -> bf16 (strided dest, vec4) ---------
__global__ __launch_bounds__(256) void gate_k(const float* __restrict__ ybf,
                                              const float* __restrict__ zx,
                                              const float* __restrict__ nw,
                                              unsigned short* __restrict__ yg,
                                              int ldyg) {
    int row = blockIdx.x;
    float4 tv[4];
    float s2 = 0.f;
#pragma unroll
    for (int i = 0; i < 4; ++i) {
        int c = (threadIdx.x + 256 * i) * 4;
        float4 y = *(const float4*)(ybf + (size_t)row * DINNER + c);
        float4 z = *(const float4*)(zx + (size_t)row * NPAD + c);
        float4 t = {y.x * siluf(z.x), y.y * siluf(z.y), y.z * siluf(z.z), y.w * siluf(z.w)};
        tv[i] = t;
        s2 += t.x * t.x + t.y * t.y + t.z * t.z + t.w * t.w;
    }
#pragma unroll
    for (int off = 32; off; off >>= 1) s2 += __shfl_down(s2, off);
    __shared__ float rs[4];
    if ((threadIdx.x & 63) == 0) rs[threadIdx.x >> 6] = s2;
    __syncthreads();
    s2 = rs[0] + rs[1] + rs[2] + rs[3];
    float scale = rsqrtf(s2 * (1.f / DINNER) + 1e-5f);
#pragma unroll
    for (int i = 0; i < 4; ++i) {
        int c = (threadIdx.x + 256 * i) * 4;
        float4 w = *(const float4*)(nw + c);
        u16x4 o = {f2bf(tv[i].x * scale * w.x), f2bf(tv[i].y * scale * w.y),
                   f2bf(tv[i].z * scale * w.z), f2bf(tv[i].w * scale * w.w)};
        *(u16x4*)(yg + (size_t)row * ldyg + c) = o;
    }
}

// ---------------- launch ----------------
extern "C" void kernel_launch(void* const* d_in, const int* in_sizes, int n_in,
                              void* d_out, int out_size, void* d_ws, size_t ws_size,
                              hipStream_t stream) {
    const float* x        = (const float*)d_in[0];
    const float* ln_w     = (const float*)d_in[1];
    const float* ln_b     = (const float*)d_in[2];
    const float* in_proj  = (const float*)d_in[3];
    const float* conv_w   = (const float*)d_in[4];
    const float* conv_b   = (const float*)d_in[5];
    const float* dt_bias  = (const float*)d_in[6];
    const float* A_log    = (const float*)d_in[7];
    const float* Dp       = (const float*)d_in[8];
    const float* norm_w   = (const float*)d_in[9];
    const float* out_proj = (const float*)d_in[10];
    float* out = (float*)d_out;
    char* ws = (char*)d_ws;

    // ---- workspace layout ----
    float*          zx   = (float*)(ws + 0);                   // 2048 x 8448 fp32
    unsigned short* wout = (unsigned short*)(ws + 69206016);
    unsigned short* win  = (unsigned short*)(ws + 85983232);
    unsigned short* ubf  = (unsigned short*)(ws + 120586240);
    float*          xin  = (float*)(ws + 85983232);            // reuses win after GEMM1
    float*          bcf  = (float*)(ws + 120586240);           // reuses ubf
    float*          dtf  = (float*)(ws + 121634816);
    float*          dtAf = (float*)(ws + 122159104);
    float*          laq  = (float*)(ws + 122683392);           // 2048 floats
    float*          Sst  = zx + 4096;                          // dead xBC cols of zx
    unsigned short* yg   = (unsigned short*)zx + 8192;         // dead cols (bf16)
    const int       ldyg = 16896;

    cvtpad_k<<<(CVT_A4 + CVT_B4) / 256, 256, 0, stream>>>(in_proj, out_proj, win, wout);
    layernorm_k<<<MROWS, 256, 0, stream>>>(x, ln_w, ln_b, ubf);
    gemm_bt<0><<<(NPAD / 128) * (MROWS / 128), 256, 0, stream>>>(ubf, win, zx, nullptr,
                                                                 NPAD, DMODEL, DMODEL,
                                                                 NPAD / 128, MROWS / 128);
    convdt_k<<<(CONV_T + MROWS * NHEADS / 4) / 256, 256, 0, stream>>>(zx, conv_w, conv_b,
                                                                      dt_bias, A_log,
                                                                      xin, bcf, dtf, dtAf);
    chunk_state_k<<<Bdim * NHEADS * NCHUNK, 256, 0, stream>>>(xin, bcf, dtf, dtAf, Sst, laq);
    combine_k<<<Bdim * NHEADS, 256, 0, stream>>>(Sst, laq);
    chunk_out_k<<<Bdim * NHEADS * NCHUNK, 256, 0, stream>>>(xin, bcf, dtf, dtAf, Sst, Dp);
    gate_k<<<MROWS, 256, 0, stream>>>(xin, zx, norm_w, yg, ldyg);
    gemm_bt<1><<<(DMODEL / 128) * (MROWS / 128), 256, 0, stream>>>(yg, wout, out, x,
                                                                   DMODEL, DINNER, ldyg,
                                                                   DMODEL / 128, MROWS / 128);
}

// Round 8
// 515.383 us; speedup vs baseline: 1.2232x; 1.0567x over previous
//
#include <hip/hip_runtime.h>
#include <hip/hip_bf16.h>

// ---------------- shapes ----------------
#define Bdim 2
#define Tdim 1024
#define DMODEL 2048
#define DSTATE 64
#define HEADDIM 64
#define DCONV 4
#define DINNER 4096
#define NHEADS 64
#define CONVDIM 4224           // DINNER + 2*DSTATE
#define DINPROJ 8384           // 2*DINNER + 2*DSTATE + NHEADS
#define NPAD 8448              // DINPROJ padded to multiple of 128
#define MROWS (Bdim*Tdim)      // 2048
#define QC 64                  // scan chunk length
#define NCHUNK (Tdim/QC)       // 16

typedef __attribute__((ext_vector_type(8))) short bf16x8;
typedef __attribute__((ext_vector_type(4))) float f32x4;
typedef __attribute__((ext_vector_type(4))) unsigned short u16x4;

#define GLB(p) ((const __attribute__((address_space(1))) void*)(p))
#define LDS(p) ((__attribute__((address_space(3))) void*)(p))

__device__ __forceinline__ unsigned short f2bf(float f) {
    unsigned int x = __builtin_bit_cast(unsigned int, f);
    x += 0x7fffu + ((x >> 16) & 1u);   // RNE
    return (unsigned short)(x >> 16);
}
__device__ __forceinline__ float bf2f(unsigned int u16) {
    unsigned int x = u16 << 16;
    return __builtin_bit_cast(float, x);
}
__device__ __forceinline__ float siluf(float v) {
    return v / (1.f + expf(-v));
}

// ------- fused fp32->bf16 weight convert (both weights, float4) -------------
#define CVT_A4 (NPAD * DMODEL / 4)        // 4,325,376
#define CVT_B4 (DMODEL * DINNER / 4)      // 2,097,152
__global__ __launch_bounds__(256) void cvtpad_k(const float* __restrict__ in_proj,
                                                const float* __restrict__ out_proj,
                                                unsigned short* __restrict__ win,
                                                unsigned short* __restrict__ wout) {
    int idx = blockIdx.x * 256 + threadIdx.x;
    if (idx < CVT_A4) {
        int i4 = idx * 4;
        int row = i4 >> 11;               // /DMODEL
        u16x4 o;
        if (row < DINPROJ) {
            float4 v = *(const float4*)(in_proj + i4);
            o = (u16x4){f2bf(v.x), f2bf(v.y), f2bf(v.z), f2bf(v.w)};
        } else {
            o = (u16x4){0, 0, 0, 0};
        }
        *(u16x4*)(win + i4) = o;
    } else {
        int i4 = (idx - CVT_A4) * 4;
        float4 v = *(const float4*)(out_proj + i4);
        *(u16x4*)(wout + i4) = (u16x4){f2bf(v.x), f2bf(v.y), f2bf(v.z), f2bf(v.w)};
    }
}

// ---------------- LayerNorm: x fp32 -> u bf16 (float4) ----------------
__global__ __launch_bounds__(256) void layernorm_k(const float* __restrict__ x,
                                                   const float* __restrict__ w,
                                                   const float* __restrict__ b,
                                                   unsigned short* __restrict__ u) {
    int row = blockIdx.x;
    const float* xr = x + (size_t)row * DMODEL;
    float4 v[2];
    float s = 0.f, s2 = 0.f;
#pragma unroll
    for (int i = 0; i < 2; ++i) {
        int c = (threadIdx.x + 256 * i) * 4;
        v[i] = *(const float4*)(xr + c);
        s += v[i].x + v[i].y + v[i].z + v[i].w;
        s2 += v[i].x * v[i].x + v[i].y * v[i].y + v[i].z * v[i].z + v[i].w * v[i].w;
    }
#pragma unroll
    for (int off = 32; off; off >>= 1) { s += __shfl_down(s, off); s2 += __shfl_down(s2, off); }
    __shared__ float rs[4], rs2[4];
    if ((threadIdx.x & 63) == 0) { rs[threadIdx.x >> 6] = s; rs2[threadIdx.x >> 6] = s2; }
    __syncthreads();
    s = rs[0] + rs[1] + rs[2] + rs[3];
    s2 = rs2[0] + rs2[1] + rs2[2] + rs2[3];
    float mu = s * (1.f / DMODEL);
    float var = s2 * (1.f / DMODEL) - mu * mu;
    float inv = rsqrtf(var + 1e-5f);
#pragma unroll
    for (int i = 0; i < 2; ++i) {
        int c = (threadIdx.x + 256 * i) * 4;
        float4 wv = *(const float4*)(w + c);
        float4 bv = *(const float4*)(b + c);
        u16x4 o = {f2bf((v[i].x - mu) * inv * wv.x + bv.x),
                   f2bf((v[i].y - mu) * inv * wv.y + bv.y),
                   f2bf((v[i].z - mu) * inv * wv.z + bv.z),
                   f2bf((v[i].w - mu) * inv * wv.w + bv.w)};
        *(u16x4*)(u + (size_t)row * DMODEL + c) = o;
    }
}

// ---------------- bf16 GEMM, B given as (N x K) row-major ("B^T" form) -------
// BK=64 K-loop (half the barriers of BK=32). LDS: element (row,kb) stored at
// 16B-chunk row*8 + (kb ^ (row&7)) -> staging is lane-contiguous (tid*16B) and
// 128B-coalesced in global; fragment ds_read_b128 is 2-way (free).
// TM: rows per block tile (128 -> 4 waves, 64 -> 2 waves). Tile N fixed = 128.
template <int EPI, int TM>
__global__ __launch_bounds__(TM * 2) void gemm_bt(const unsigned short* __restrict__ A,
                                                  const unsigned short* __restrict__ Bw,
                                                  float* __restrict__ Cout,
                                                  const float* __restrict__ resid,
                                                  int N, int Kloop, int lda, int ldb,
                                                  int nb, int mb) {
    const int NT = TM * 2;   // threads per block
    // panel swizzle (8 n-tiles per panel) for L2 reuse
    const int bid = blockIdx.x;
    const int per_panel = mb * 8;
    const int fullp = (nb / 8) * per_panel;
    int mt, nt;
    if (bid < fullp) {
        int p = bid / per_panel, r = bid % per_panel;
        nt = p * 8 + r / mb; mt = r % mb;
    } else {
        int r = bid - fullp;
        nt = (nb / 8) * 8 + r / mb; mt = r % mb;
    }
    const int m0 = mt * TM, n0 = nt * 128;

    __shared__ unsigned short As[TM * 64];    // TM rows x 64 k (xor-swizzled chunks)
    __shared__ unsigned short Bs[128 * 64];
    const int tid = threadIdx.x;
    const int lane = tid & 63, w = tid >> 6;
    const int wm = (w >> 1) * 64, wn = (w & 1) * 64;
    const int row16 = lane & 15, quad = lane >> 4;

    // staging maps: chunk c -> row=c>>3, group g=c&7, kb = g ^ (row&7)
    const int NAL = (TM * 8) / NT;            // A chunks per thread (=4)
    const int NBL = 1024 / NT;                // B chunks per thread (4 or 8)
    const unsigned short* gA[NAL];
    const unsigned short* gB[NBL];
#pragma unroll
    for (int l = 0; l < NAL; ++l) {
        int c = l * NT + tid;
        int r = c >> 3, kb = (c & 7) ^ (r & 7);
        gA[l] = A + (size_t)(m0 + r) * lda + kb * 8;
    }
#pragma unroll
    for (int l = 0; l < NBL; ++l) {
        int c = l * NT + tid;
        int r = c >> 3, kb = (c & 7) ^ (r & 7);
        gB[l] = Bw + (size_t)(n0 + r) * ldb + kb * 8;
    }

    f32x4 acc[4][4];
#pragma unroll
    for (int i = 0; i < 4; ++i)
#pragma unroll
        for (int j = 0; j < 4; ++j) acc[i][j] = (f32x4){0.f, 0.f, 0.f, 0.f};

    const int swz = row16 & 7;
    for (int k0 = 0; k0 < Kloop; k0 += 64) {
#pragma unroll
        for (int l = 0; l < NAL; ++l)
            __builtin_amdgcn_global_load_lds(GLB(gA[l] + k0), LDS(As + (l * NT + tid) * 8), 16, 0, 0);
#pragma unroll
        for (int l = 0; l < NBL; ++l)
            __builtin_amdgcn_global_load_lds(GLB(gB[l] + k0), LDS(Bs + (l * NT + tid) * 8), 16, 0, 0);
        __syncthreads();

#pragma unroll
        for (int s = 0; s < 2; ++s) {
            const int g = (s * 4 + quad) ^ swz;
            bf16x8 af[4], bfr[4];
#pragma unroll
            for (int i = 0; i < 4; ++i)
                af[i] = *(const bf16x8*)&As[((wm + i * 16 + row16) * 8 + g) * 8];
#pragma unroll
            for (int j = 0; j < 4; ++j)
                bfr[j] = *(const bf16x8*)&Bs[((wn + j * 16 + row16) * 8 + g) * 8];
#pragma unroll
            for (int i = 0; i < 4; ++i)
#pragma unroll
                for (int j = 0; j < 4; ++j)
                    acc[i][j] = __builtin_amdgcn_mfma_f32_16x16x32_bf16(af[i], bfr[j], acc[i][j], 0, 0, 0);
        }
        __syncthreads();
    }

#pragma unroll
    for (int i = 0; i < 4; ++i)
#pragma unroll
        for (int j = 0; j < 4; ++j)
#pragma unroll
            for (int r = 0; r < 4; ++r) {
                int m = m0 + wm + i * 16 + quad * 4 + r;
                int n = n0 + wn + j * 16 + row16;
                float v = acc[i][j][r];
                if (EPI == 0)
                    Cout[(size_t)m * N + n] = v;
                else
                    Cout[(size_t)m * N + n] = resid[(size_t)m * N + n] + v;
            }
}

// -------- fused causal conv4+SiLU (vec4) + dt/softplus (vec4) ----------------
#define CONV_T (MROWS * CONVDIM / 4)      // 2,162,688
__global__ __launch_bounds__(256) void convdt_k(const float* __restrict__ zx,
                                                const float* __restrict__ cw,
                                                const float* __restrict__ cb,
                                                const float* __restrict__ dt_bias,
                                                const float* __restrict__ A_log,
                                                float* __restrict__ xin,
                                                float* __restrict__ bcf,
                                                float* __restrict__ dtf,
                                                float* __restrict__ dtAf) {
    int idx = blockIdx.x * 256 + threadIdx.x;
    if (idx < CONV_T) {
        int cg = idx % (CONVDIM / 4);
        int bt = idx / (CONVDIM / 4);
        int c = cg * 4;
        int t = bt & (Tdim - 1);
        const float* base = zx + (size_t)bt * NPAD + DINNER + c;
        float4 acc = *(const float4*)(cb + c);
#pragma unroll
        for (int kk = 0; kk < DCONV; ++kk) {
            int tt = t - 3 + kk;
            if (tt >= 0) {
                float4 v = *(const float4*)(base + (long)(kk - 3) * NPAD);
                acc.x += v.x * cw[(c + 0) * 4 + kk];
                acc.y += v.y * cw[(c + 1) * 4 + kk];
                acc.z += v.z * cw[(c + 2) * 4 + kk];
                acc.w += v.w * cw[(c + 3) * 4 + kk];
            }
        }
        float4 s = {siluf(acc.x), siluf(acc.y), siluf(acc.z), siluf(acc.w)};
        if (c < DINNER) *(float4*)(xin + (size_t)bt * DINNER + c) = s;
        else            *(float4*)(bcf + (size_t)bt * 128 + (c - DINNER)) = s;
    } else {
        int d4 = (idx - CONV_T) * 4;
        int bt = d4 >> 6;
        int h = d4 & 63;
        float4 raw = *(const float4*)(zx + (size_t)bt * NPAD + (DINNER + CONVDIM) + h);
        float4 bias = *(const float4*)(dt_bias + h);
        float4 al = *(const float4*)(A_log + h);
        float r[4] = {raw.x + bias.x, raw.y + bias.y, raw.z + bias.z, raw.w + bias.w};
        float A[4] = {-expf(al.x), -expf(al.y), -expf(al.z), -expf(al.w)};
        float4 dtv, dta;
        float* dtp = (float*)&dtv; float* dap = (float*)&dta;
#pragma unroll
        for (int j = 0; j < 4; ++j) {
            float dv = (r[j] > 20.f) ? r[j] : log1pf(expf(r[j]));
            dtp[j] = dv;
            dap[j] = dv * A[j];
        }
        *(float4*)(dtf + bt * 64 + h) = dtv;
        *(float4*)(dtAf + bt * 64 + h) = dta;
    }
}

// ============ chunked SSM scan (SSD decomposition), Q=64 =====================
__global__ __launch_bounds__(256) void chunk_state_k(const float* __restrict__ xin,
                                                     const float* __restrict__ bcf,
                                                     const float* __restrict__ dtf,
                                                     const float* __restrict__ dtAf,
                                                     float* __restrict__ Sst,
                                                     float* __restrict__ laq) {
    const int blk = blockIdx.x;
    const int c = blk & 15, h = (blk >> 4) & 63, b = blk >> 10;
    const int bt0 = b * Tdim + c * QC;
    const int tid = threadIdx.x;

    __shared__ float Bs[QC][68];
    __shared__ float Dx[QC][68];
    __shared__ float wsh[QC];

    if (tid < QC) {
        float v = dtAf[(bt0 + tid) * NHEADS + h];
#pragma unroll
        for (int d = 1; d < 64; d <<= 1) {
            float o = __shfl_up(v, d, 64);
            v += (tid >= d) ? o : 0.f;
        }
        float la63 = __shfl(v, 63, 64);
        wsh[tid] = expf(la63 - v);
        if (tid == 63) laq[blk] = la63;
    }
    __syncthreads();

    const int row = tid >> 2, q = tid & 3;
    {
        float m = wsh[row] * dtf[(bt0 + row) * NHEADS + h];
        const float* xr = xin + (size_t)(bt0 + row) * DINNER + h * 64 + q * 16;
        const float* br = bcf + (size_t)(bt0 + row) * 128 + q * 16;
#pragma unroll
        for (int j = 0; j < 4; ++j) {
            float4 xv = *(const float4*)(xr + j * 4);
            float4 bv = *(const float4*)(br + j * 4);
            *(float4*)&Dx[row][q * 16 + j * 4] = (float4){m * xv.x, m * xv.y, m * xv.z, m * xv.w};
            *(float4*)&Bs[row][q * 16 + j * 4] = bv;
        }
    }
    __syncthreads();

    const int p0 = (tid >> 4) * 4, n0 = (tid & 15) * 4;
    float acc[4][4] = {};
    for (int i = 0; i < QC; ++i) {
        float4 dv = *(const float4*)&Dx[i][p0];
        float4 bv = *(const float4*)&Bs[i][n0];
        float dva[4] = {dv.x, dv.y, dv.z, dv.w};
        float bva[4] = {bv.x, bv.y, bv.z, bv.w};
#pragma unroll
        for (int a = 0; a < 4; ++a)
#pragma unroll
            for (int e = 0; e < 4; ++e) acc[a][e] += dva[a] * bva[e];
    }
    float* Sp = Sst + (size_t)blk * NPAD;
#pragma unroll
    for (int a = 0; a < 4; ++a)
        *(float4*)&Sp[(p0 + a) * 64 + n0] = (float4){acc[a][0], acc[a][1], acc[a][2], acc[a][3]};
}

// Phase B: 256 blocks, each handles half (32 rows) of one (b,h) state prefix
__global__ __launch_bounds__(256) void combine_k(float* __restrict__ Sst,
                                                 const float* __restrict__ laq) {
    const int bh = blockIdx.x >> 1;
    const int half = blockIdx.x & 1;
    const int tid = threadIdx.x;
    float4 r0 = {}, r1 = {};
    for (int c = 0; c < NCHUNK - 1; ++c) {
        float* p = Sst + (size_t)(bh * 16 + c) * NPAD + half * 2048 + tid * 8;
        float P = expf(laq[bh * 16 + c]);
        float4 s0 = ((const float4*)p)[0], s1 = ((const float4*)p)[1];
        r0 = (float4){P * r0.x + s0.x, P * r0.y + s0.y, P * r0.z + s0.z, P * r0.w + s0.w};
        r1 = (float4){P * r1.x + s1.x, P * r1.y + s1.y, P * r1.z + s1.z, P * r1.w + s1.w};
        ((float4*)p)[0] = r0; ((float4*)p)[1] = r1;
    }
}

__global__ __launch_bounds__(256) void chunk_out_k(float* __restrict__ xin,
                                                   const float* __restrict__ bcf,
                                                   const float* __restrict__ dtf,
                                                   const float* __restrict__ dtAf,
                                                   const float* __restrict__ Sst,
                                                   const float* __restrict__ Dp) {
    const int blk = blockIdx.x;
    const int c = blk & 15, h = (blk >> 4) & 63, b = blk >> 10;
    const int bt0 = b * Tdim + c * QC;
    const int tid = threadIdx.x;

    __shared__ float Cs[QC][68];
    __shared__ float BsT[QC][68];
    __shared__ unsigned short Dxh[QC][72];
    __shared__ float G[QC][68];
    __shared__ float lash[QC];

    if (tid < QC) {
        float v = dtAf[(bt0 + tid) * NHEADS + h];
#pragma unroll
        for (int d = 1; d < 64; d <<= 1) {
            float o = __shfl_up(v, d, 64);
            v += (tid >= d) ? o : 0.f;
        }
        lash[tid] = v;
    }

    const int row = tid >> 2, q = tid & 3;
    {
        float m = dtf[(bt0 + row) * NHEADS + h];
        const float* xr = xin + (size_t)(bt0 + row) * DINNER + h * 64 + q * 16;
        const float* br = bcf + (size_t)(bt0 + row) * 128 + q * 16;
        const float* cr = bcf + (size_t)(bt0 + row) * 128 + 64 + q * 16;
#pragma unroll
        for (int j = 0; j < 4; ++j) {
            float4 xv = *(const float4*)(xr + j * 4);
            float4 bv = *(const float4*)(br + j * 4);
            float4 cv = *(const float4*)(cr + j * 4);
            unsigned int w0 = (unsigned int)f2bf(m * xv.x) | ((unsigned int)f2bf(m * xv.y) << 16);
            unsigned int w1 = (unsigned int)f2bf(m * xv.z) | ((unsigned int)f2bf(m * xv.w) << 16);
            *(uint2*)&Dxh[row][q * 16 + j * 4] = (uint2){w0, w1};
            *(float4*)&Cs[row][q * 16 + j * 4] = cv;
            int n = q * 16 + j * 4;
            BsT[n + 0][row] = bv.x; BsT[n + 1][row] = bv.y;
            BsT[n + 2][row] = bv.z; BsT[n + 3][row] = bv.w;
        }
    }
    __syncthreads();

    const int t0 = (tid >> 4) * 4, s0 = (tid & 15) * 4;
    {
        float acc[4][4] = {};
        for (int n = 0; n < 64; ++n) {
            float4 bv = *(const float4*)&BsT[n][s0];
            float bva[4] = {bv.x, bv.y, bv.z, bv.w};
            float cva[4] = {Cs[t0 + 0][n], Cs[t0 + 1][n], Cs[t0 + 2][n], Cs[t0 + 3][n]};
#pragma unroll
            for (int a = 0; a < 4; ++a)
#pragma unroll
                for (int e = 0; e < 4; ++e) acc[a][e] += cva[a] * bva[e];
        }
        float lat[4] = {lash[t0 + 0], lash[t0 + 1], lash[t0 + 2], lash[t0 + 3]};
#pragma unroll
        for (int a = 0; a < 4; ++a)
#pragma unroll
            for (int e = 0; e < 4; ++e) {
                int t = t0 + a, s = s0 + e;
                G[t][s] = (s <= t) ? acc[a][e] * expf(lat[a] - lash[s]) : 0.f;
            }
    }
    __syncthreads();

    if (c > 0) {
        const float* Hp = Sst + (size_t)(blk - 1) * NPAD;
#pragma unroll
        for (int j = 0; j < 4; ++j) {
            float4 hv = *(const float4*)&Hp[row * 64 + q * 16 + j * 4];
            int n = q * 16 + j * 4;
            BsT[n + 0][row] = hv.x; BsT[n + 1][row] = hv.y;
            BsT[n + 2][row] = hv.z; BsT[n + 3][row] = hv.w;
        }
    }
    __syncthreads();

    const int p0 = (tid & 15) * 4;
    float accS[4][4] = {};
    for (int s = 0; s < 64; ++s) {
        uint2 dw = *(const uint2*)&Dxh[s][p0];
        float dva[4] = {bf2f(dw.x & 0xffffu), bf2f(dw.x >> 16),
                        bf2f(dw.y & 0xffffu), bf2f(dw.y >> 16)};
        float gva[4] = {G[t0 + 0][s], G[t0 + 1][s], G[t0 + 2][s], G[t0 + 3][s]};
#pragma unroll
        for (int a = 0; a < 4; ++a)
#pragma unroll
            for (int e = 0; e < 4; ++e) accS[a][e] += gva[a] * dva[e];
    }
    float accH[4][4] = {};
    if (c > 0) {
        for (int n = 0; n < 64; ++n) {
            float4 hv = *(const float4*)&BsT[n][p0];
            float hva[4] = {hv.x, hv.y, hv.z, hv.w};
            float cva[4] = {Cs[t0 + 0][n], Cs[t0 + 1][n], Cs[t0 + 2][n], Cs[t0 + 3][n]};
#pragma unroll
            for (int a = 0; a < 4; ++a)
#pragma unroll
                for (int e = 0; e < 4; ++e) accH[a][e] += cva[a] * hva[e];
        }
    }
    float Dh = Dp[h];
    float eA[4] = {expf(lash[t0 + 0]), expf(lash[t0 + 1]), expf(lash[t0 + 2]), expf(lash[t0 + 3])};
#pragma unroll
    for (int a = 0; a < 4; ++a) {
        float* xr = xin + (size_t)(bt0 + t0 + a) * DINNER + h * 64 + p0;
        float4 xv = *(const float4*)xr;
        float4 yv;
        yv.x = accS[a][0] + eA[a] * accH[a][0] + Dh * xv.x;
        yv.y = accS[a][1] + eA[a] * accH[a][1] + Dh * xv.y;
        yv.z = accS[a][2] + eA[a] * accH[a][2] + Dh * xv.z;
        yv.w = accS[a][3] + eA[a] * accH[a][3] + Dh * xv.w;
        *(float4*)xr = yv;
    }
}

// ---------------- y * silu(z), RMSNorm, -> bf16 (strided dest, vec4) ---------
__global__ __launch_bounds__(256) void gate_k(const float* __restrict__ ybf,
                                              const float* __restrict__ zx,
                                              const float* __restrict__ nw,
                                              unsigned short* __restrict__ yg,
                                              int ldyg) {
    int row = blockIdx.x;
    float4 tv[4];
    float s2 = 0.f;
#pragma unroll
    for (int i = 0; i < 4; ++i) {
        int c = (threadIdx.x + 256 * i) * 4;
        float4 y = *(const float4*)(ybf + (size_t)row * DINNER + c);
        float4 z = *(const float4*)(zx + (size_t)row * NPAD + c);
        float4 t = {y.x * siluf(z.x), y.y * siluf(z.y), y.z * siluf(z.z), y.w * siluf(z.w)};
        tv[i] = t;
        s2 += t.x * t.x + t.y * t.y + t.z * t.z + t.w * t.w;
    }
#pragma unroll
    for (int off = 32; off; off >>= 1) s2 += __shfl_down(s2, off);
    __shared__ float rs[4];
    if ((threadIdx.x & 63) == 0) rs[threadIdx.x >> 6] = s2;
    __syncthreads();
    s2 = rs[0] + rs[1] + rs[2] + rs[3];
    float scale = rsqrtf(s2 * (1.f / DINNER) + 1e-5f);
#pragma unroll
    for (int i = 0; i < 4; ++i) {
        int c = (threadIdx.x + 256 * i) * 4;
        float4 w = *(const float4*)(nw + c);
        u16x4 o = {f2bf(tv[i].x * scale * w.x), f2bf(tv[i].y * scale * w.y),
                   f2bf(tv[i].z * scale * w.z), f2bf(tv[i].w * scale * w.w)};
        *(u16x4*)(yg + (size_t)row * ldyg + c) = o;
    }
}

// ---------------- launch ----------------
extern "C" void kernel_launch(void* const* d_in, const int* in_sizes, int n_in,
                              void* d_out, int out_size, void* d_ws, size_t ws_size,
                              hipStream_t stream) {
    const float* x        = (const float*)d_in[0];
    const float* ln_w     = (const float*)d_in[1];
    const float* ln_b     = (const float*)d_in[2];
    const float* in_proj  = (const float*)d_in[3];
    const float* conv_w   = (const float*)d_in[4];
    const float* conv_b   = (const float*)d_in[5];
    const float* dt_bias  = (const float*)d_in[6];
    const float* A_log    = (const float*)d_in[7];
    const float* Dp       = (const float*)d_in[8];
    const float* norm_w   = (const float*)d_in[9];
    const float* out_proj = (const float*)d_in[10];
    float* out = (float*)d_out;
    char* ws = (char*)d_ws;

    // ---- workspace layout ----
    float*          zx   = (float*)(ws + 0);                   // 2048 x 8448 fp32
    unsigned short* wout = (unsigned short*)(ws + 69206016);
    unsigned short* win  = (unsigned short*)(ws + 85983232);
    unsigned short* ubf  = (unsigned short*)(ws + 120586240);
    float*          xin  = (float*)(ws + 85983232);            // reuses win after GEMM1
    float*          bcf  = (float*)(ws + 120586240);           // reuses ubf
    float*          dtf  = (float*)(ws + 121634816);
    float*          dtAf = (float*)(ws + 122159104);
    float*          laq  = (float*)(ws + 122683392);           // 2048 floats
    float*          Sst  = zx + 4096;                          // dead xBC cols of zx
    unsigned short* yg   = (unsigned short*)zx + 8192;         // dead cols (bf16)
    const int       ldyg = 16896;

    cvtpad_k<<<(CVT_A4 + CVT_B4) / 256, 256, 0, stream>>>(in_proj, out_proj, win, wout);
    layernorm_k<<<MROWS, 256, 0, stream>>>(x, ln_w, ln_b, ubf);
    // GEMM1: M=2048 (mb=16, TM=128), N=8448 (nb=66), K=2048
    gemm_bt<0, 128><<<66 * 16, 256, 0, stream>>>(ubf, win, zx, nullptr,
                                                 NPAD, DMODEL, DMODEL, DMODEL, 66, 16);
    convdt_k<<<(CONV_T + MROWS * NHEADS / 4) / 256, 256, 0, stream>>>(zx, conv_w, conv_b,
                                                                      dt_bias, A_log,
                                                                      xin, bcf, dtf, dtAf);
    chunk_state_k<<<Bdim * NHEADS * NCHUNK, 256, 0, stream>>>(xin, bcf, dtf, dtAf, Sst, laq);
    combine_k<<<2 * Bdim * NHEADS, 256, 0, stream>>>(Sst, laq);
    chunk_out_k<<<Bdim * NHEADS * NCHUNK, 256, 0, stream>>>(xin, bcf, dtf, dtAf, Sst, Dp);
    gate_k<<<MROWS, 256, 0, stream>>>(xin, zx, norm_w, yg, ldyg);
    // GEMM2: M=2048 (mb=32, TM=64), N=2048 (nb=16), K=4096 -> 512 blocks
    gemm_bt<1, 64><<<16 * 32, 128, 0, stream>>>(yg, wout, out, x,
                                                DMODEL, DINNER, ldyg, DINNER, 16, 32);
}